// Round 1
// baseline (2390.539 us; speedup 1.0000x reference)
//
#include <hip/hip_runtime.h>
#include <math.h>

#define BN_EPS 1e-5f

// ---------- helpers ----------

__device__ __forceinline__ float siluf(float v) {
    return v / (1.0f + __expf(-v));
}

// Cubic B-spline basis (4 funcs) on uniform knots g[j] = 2*j - 7, j=0..7.
// Exact Cox-de Boor recursion matching the reference.
__device__ __forceinline__ void bspline4(float x, float b3[4]) {
    float b0[7];
#pragma unroll
    for (int j = 0; j < 7; ++j) {
        float gj = 2.0f * (float)j - 7.0f;
        b0[j] = (x >= gj && x < gj + 2.0f) ? 1.0f : 0.0f;
    }
    float b1[6];
#pragma unroll
    for (int j = 0; j < 6; ++j) {
        float gj = 2.0f * (float)j - 7.0f;
        b1[j] = (x - gj) * 0.5f * b0[j] + (gj + 4.0f - x) * 0.5f * b0[j + 1];
    }
    float b2[5];
#pragma unroll
    for (int j = 0; j < 5; ++j) {
        float gj = 2.0f * (float)j - 7.0f;
        b2[j] = (x - gj) * 0.25f * b1[j] + (gj + 6.0f - x) * 0.25f * b1[j + 1];
    }
#pragma unroll
    for (int j = 0; j < 4; ++j) {
        float gj = 2.0f * (float)j - 7.0f;
        b3[j] = (x - gj) * (1.0f / 6.0f) * b2[j] + (gj + 8.0f - x) * (1.0f / 6.0f) * b2[j + 1];
    }
}

// ---------- conv1: [1024,3,32,32] -> h1 [1024,32,31,31] ----------

__global__ __launch_bounds__(256) void conv1_kernel(
        const float* __restrict__ x, const float* __restrict__ bw,
        const float* __restrict__ sw, float* __restrict__ h1) {
    int t = blockIdx.x * 256 + threadIdx.x;
    if (t >= 1024 * 31 * 31) return;
    int px = t % 31;
    int py = (t / 31) % 31;
    int b  = t / 961;
    const float* xb = x + (size_t)b * 3 * 1024;
    float acc[32];
#pragma unroll
    for (int o = 0; o < 32; ++o) acc[o] = 0.0f;
#pragma unroll
    for (int c = 0; c < 3; ++c) {
#pragma unroll
        for (int dy = 0; dy < 2; ++dy) {
#pragma unroll
            for (int dx = 0; dx < 2; ++dx) {
                int i = c * 4 + dy * 2 + dx;   // patch feature index (channel-major)
                float v = xb[c * 1024 + (py + dy) * 32 + (px + dx)];
                float f0 = siluf(v);
                float fb[4];
                bspline4(v, fb);
#pragma unroll
                for (int o = 0; o < 32; ++o) {
                    float a = acc[o];
                    a += f0    * bw[o * 12 + i];
                    a += fb[0] * sw[(o * 12 + i) * 4 + 0];
                    a += fb[1] * sw[(o * 12 + i) * 4 + 1];
                    a += fb[2] * sw[(o * 12 + i) * 4 + 2];
                    a += fb[3] * sw[(o * 12 + i) * 4 + 3];
                    acc[o] = a;
                }
            }
        }
    }
    size_t base = (size_t)b * 32 * 961 + (size_t)py * 31 + px;
#pragma unroll
    for (int o = 0; o < 32; ++o) h1[base + (size_t)o * 961] = acc[o];
}

// ---------- conv2: pooled1 [1024,32,15,15] -> h2 [1024,64,14,14] ----------

__global__ __launch_bounds__(256) void conv2_kernel(
        const float* __restrict__ p1, const float* __restrict__ bw,
        const float* __restrict__ sw, float* __restrict__ h2) {
    int t = blockIdx.x * 256 + threadIdx.x;
    if (t >= 1024 * 14 * 14) return;
    int px = t % 14;
    int py = (t / 14) % 14;
    int b  = t / 196;
    float acc[64];
#pragma unroll
    for (int o = 0; o < 64; ++o) acc[o] = 0.0f;
    for (int c = 0; c < 32; ++c) {
        const float* pc = p1 + ((size_t)b * 32 + c) * 225 + py * 15 + px;
        float f[4][5];
#pragma unroll
        for (int dy = 0; dy < 2; ++dy) {
#pragma unroll
            for (int dx = 0; dx < 2; ++dx) {
                int s = dy * 2 + dx;
                float v = pc[dy * 15 + dx];
                f[s][0] = siluf(v);
                bspline4(v, &f[s][1]);
            }
        }
        const float* bwc = bw + c * 4;    // bw[o*128 + c*4 + s]
        const float* swc = sw + c * 16;   // sw[o*512 + c*16 + s*4 + k]
#pragma unroll
        for (int o = 0; o < 64; ++o) {
            float a = acc[o];
#pragma unroll
            for (int s = 0; s < 4; ++s) {
                a += f[s][0] * bwc[o * 128 + s];
                a += f[s][1] * swc[o * 512 + s * 4 + 0];
                a += f[s][2] * swc[o * 512 + s * 4 + 1];
                a += f[s][3] * swc[o * 512 + s * 4 + 2];
                a += f[s][4] * swc[o * 512 + s * 4 + 3];
            }
            acc[o] = a;
        }
    }
    size_t base = (size_t)b * 64 * 196 + (size_t)py * 14 + px;
#pragma unroll
    for (int o = 0; o < 64; ++o) h2[base + (size_t)o * 196] = acc[o];
}

// ---------- per-channel sum / sumsq (atomic partials) ----------

__global__ __launch_bounds__(128) void chan_stats_kernel(
        const float* __restrict__ src, float* __restrict__ stats, int C, int HW) {
    int c = blockIdx.x, b = blockIdx.y;
    const float* p = src + ((size_t)b * C + c) * HW;
    float s = 0.f, s2 = 0.f;
    for (int j = threadIdx.x; j < HW; j += 128) {
        float v = p[j];
        s += v; s2 += v * v;
    }
#pragma unroll
    for (int off = 32; off > 0; off >>= 1) {
        s  += __shfl_down(s, off, 64);
        s2 += __shfl_down(s2, off, 64);
    }
    __shared__ float ls[4];
    if ((threadIdx.x & 63) == 0) {
        ls[(threadIdx.x >> 6) * 2]     = s;
        ls[(threadIdx.x >> 6) * 2 + 1] = s2;
    }
    __syncthreads();
    if (threadIdx.x == 0) {
        atomicAdd(&stats[2 * c],     ls[0] + ls[2]);
        atomicAdd(&stats[2 * c + 1], ls[1] + ls[3]);
    }
}

// ---------- fused BN + ReLU + 2x2 maxpool ----------

__global__ __launch_bounds__(256) void bnpool_kernel(
        const float* __restrict__ h, const float* __restrict__ stats,
        const float* __restrict__ g, const float* __restrict__ bb,
        float* __restrict__ out, int C, int H, int W, int PH, int PW,
        float invN, int total) {
    int t = blockIdx.x * 256 + threadIdx.x;
    if (t >= total) return;
    int px = t % PW;
    int py = (t / PW) % PH;
    int c  = (t / (PW * PH)) % C;
    int b  = t / (PW * PH * C);
    float mean = stats[2 * c] * invN;
    float var  = stats[2 * c + 1] * invN - mean * mean;
    float sc = rsqrtf(var + BN_EPS) * g[c];
    float sh = bb[c] - mean * sc;
    const float* hp = h + (((size_t)b * C + c) * H + 2 * py) * W + 2 * px;
    float v0 = fmaxf(hp[0] * sc + sh, 0.f);
    float v1 = fmaxf(hp[1] * sc + sh, 0.f);
    float v2 = fmaxf(hp[W] * sc + sh, 0.f);
    float v3 = fmaxf(hp[W + 1] * sc + sh, 0.f);
    out[t] = fmaxf(fmaxf(v0, v1), fmaxf(v2, v3));
}

// ---------- transpose fc1_w [64,3136] -> wT [3136,64] ----------

__global__ __launch_bounds__(256) void transpose_kernel(
        const float* __restrict__ w, float* __restrict__ wT) {
    int t = blockIdx.x * 256 + threadIdx.x;
    if (t >= 64 * 3136) return;
    int o = t & 63;
    int k = t >> 6;
    wT[(size_t)k * 64 + o] = w[(size_t)o * 3136 + k];
}

// ---------- fc1: pooled2 flat [1024,3136] @ wT -> z [1024,64] ----------

__global__ __launch_bounds__(256) void fc1_kernel(
        const float* __restrict__ xin, const float* __restrict__ wT,
        const float* __restrict__ bias, float* __restrict__ z) {
    __shared__ float xs[4 * 3136];
    __shared__ float red[4][4][64];
    int b0 = blockIdx.x * 4;
    for (int j = threadIdx.x; j < 4 * 3136; j += 256)
        xs[j] = xin[(size_t)b0 * 3136 + j];
    __syncthreads();
    int o = threadIdx.x & 63, q = threadIdx.x >> 6;
    float s0 = 0.f, s1 = 0.f, s2 = 0.f, s3 = 0.f;
    for (int j = q * 784; j < q * 784 + 784; ++j) {
        float wv = wT[(size_t)j * 64 + o];
        s0 += xs[j] * wv;
        s1 += xs[3136 + j] * wv;
        s2 += xs[2 * 3136 + j] * wv;
        s3 += xs[3 * 3136 + j] * wv;
    }
    red[0][q][o] = s0; red[1][q][o] = s1; red[2][q][o] = s2; red[3][q][o] = s3;
    __syncthreads();
    int bb = threadIdx.x >> 6;
    float tot = red[bb][0][o] + red[bb][1][o] + red[bb][2][o] + red[bb][3][o] + bias[o];
    z[((size_t)(b0 + bb)) * 64 + o] = tot;
}

// ---------- bn1d column stats over z [1024,64] ----------

__global__ __launch_bounds__(256) void colstats_kernel(
        const float* __restrict__ z, float* __restrict__ stats) {
    int c = blockIdx.x;
    float s = 0.f, s2 = 0.f;
    for (int b = threadIdx.x; b < 1024; b += 256) {
        float v = z[(size_t)b * 64 + c];
        s += v; s2 += v * v;
    }
#pragma unroll
    for (int off = 32; off > 0; off >>= 1) {
        s  += __shfl_down(s, off, 64);
        s2 += __shfl_down(s2, off, 64);
    }
    __shared__ float ls[8];
    int w = threadIdx.x >> 6;
    if ((threadIdx.x & 63) == 0) { ls[w * 2] = s; ls[w * 2 + 1] = s2; }
    __syncthreads();
    if (threadIdx.x == 0) {
        stats[2 * c]     = ls[0] + ls[2] + ls[4] + ls[6];
        stats[2 * c + 1] = ls[1] + ls[3] + ls[5] + ls[7];
    }
}

// ---------- final: bn1d + relu + fc2 -> out [1024,10] ----------

__global__ __launch_bounds__(256) void final_kernel(
        const float* __restrict__ z, const float* __restrict__ stats,
        const float* __restrict__ g, const float* __restrict__ bb,
        const float* __restrict__ w2, const float* __restrict__ b2,
        float* __restrict__ out) {
    int t = blockIdx.x * 256 + threadIdx.x;
    if (t >= 10240) return;
    int o = t % 10, b = t / 10;
    float acc = b2[o];
#pragma unroll 8
    for (int c = 0; c < 64; ++c) {
        float mean = stats[2 * c] * (1.0f / 1024.0f);
        float var  = stats[2 * c + 1] * (1.0f / 1024.0f) - mean * mean;
        float sc = rsqrtf(var + BN_EPS) * g[c];
        float a = fmaxf(z[(size_t)b * 64 + c] * sc + (bb[c] - mean * sc), 0.f);
        acc += a * w2[o * 64 + c];
    }
    out[t] = acc;
}

// ---------- launch ----------

extern "C" void kernel_launch(void* const* d_in, const int* in_sizes, int n_in,
                              void* d_out, int out_size, void* d_ws, size_t ws_size,
                              hipStream_t stream) {
    const float* x   = (const float*)d_in[0];
    const float* bw1 = (const float*)d_in[1];
    const float* sw1 = (const float*)d_in[2];
    const float* g1  = (const float*)d_in[3];
    const float* b1  = (const float*)d_in[4];
    const float* bw2 = (const float*)d_in[5];
    const float* sw2 = (const float*)d_in[6];
    const float* g2  = (const float*)d_in[7];
    const float* b2v = (const float*)d_in[8];
    const float* fw1 = (const float*)d_in[9];
    const float* fb1 = (const float*)d_in[10];
    const float* g3  = (const float*)d_in[11];
    const float* b3  = (const float*)d_in[12];
    const float* fw2 = (const float*)d_in[13];
    const float* fb2 = (const float*)d_in[14];
    float* out = (float*)d_out;

    char* ws = (char*)d_ws;
    // region A: h1 [1024,32,31,31] (126 MB), reused as h2 [1024,64,14,14]
    float* h1     = (float*)(ws);
    // region B: pooled1 [1024,32,15,15] (29.5 MB), reused as pooled2 [1024,64,7,7]
    float* pooled = (float*)(ws + 125960192);
    float* z      = (float*)(ws + 155451392);   // [1024,64]
    float* wT     = (float*)(ws + 155713536);   // [3136,64]
    float* stats1 = (float*)(ws + 156516352);   // 32*2 floats
    float* stats2 = (float*)(ws + 156516608);   // 64*2 floats
    float* stats3 = (float*)(ws + 156517120);   // 64*2 floats

    hipMemsetAsync(ws + 156516352, 0, 1280, stream);

    transpose_kernel<<<(64 * 3136 + 255) / 256, 256, 0, stream>>>(fw1, wT);

    conv1_kernel<<<(1024 * 961 + 255) / 256, 256, 0, stream>>>(x, bw1, sw1, h1);

    {
        dim3 grid(32, 1024);
        chan_stats_kernel<<<grid, 128, 0, stream>>>(h1, stats1, 32, 961);
    }
    bnpool_kernel<<<(1024 * 32 * 225 + 255) / 256, 256, 0, stream>>>(
        h1, stats1, g1, b1, pooled, 32, 31, 31, 15, 15,
        1.0f / (1024.0f * 961.0f), 1024 * 32 * 225);

    float* h2 = h1;  // region A reuse
    conv2_kernel<<<(1024 * 196 + 255) / 256, 256, 0, stream>>>(pooled, bw2, sw2, h2);

    {
        dim3 grid(64, 1024);
        chan_stats_kernel<<<grid, 128, 0, stream>>>(h2, stats2, 64, 196);
    }
    float* pooled2 = pooled;  // region B reuse
    bnpool_kernel<<<(1024 * 64 * 49 + 255) / 256, 256, 0, stream>>>(
        h2, stats2, g2, b2v, pooled2, 64, 14, 14, 7, 7,
        1.0f / (1024.0f * 196.0f), 1024 * 64 * 49);

    fc1_kernel<<<256, 256, 0, stream>>>(pooled2, wT, fb1, z);
    colstats_kernel<<<64, 256, 0, stream>>>(z, stats3);
    final_kernel<<<(10240 + 255) / 256, 256, 0, stream>>>(z, stats3, g3, b3, fw2, fb2, out);
}